// Round 19
// baseline (323.651 us; speedup 1.0000x reference)
//
#include <hip/hip_runtime.h>
#include <hip/hip_bf16.h>
#include <cstdint>
#include <cstddef>

#define EMBED 768
#define STREAMS 4
#define CHUNK 192          // EMBED / STREAMS
#define HEADS 12
#define HD 64
#define SEQ 1024
#define BATCH 8
#define TOKENS (BATCH * SEQ)   // 8192
#define MLPH 3072

typedef __bf16 bf16;
typedef __bf16 bf16x4 __attribute__((ext_vector_type(4)));
typedef __bf16 bf16x8 __attribute__((ext_vector_type(8)));
typedef float f32x4 __attribute__((ext_vector_type(4)));
typedef float f32x16 __attribute__((ext_vector_type(16)));

// async global->LDS, 16B per lane; LDS dest must be linear in lane order
#define GLDS16(gp, lp)                                                        \
  __builtin_amdgcn_global_load_lds(                                           \
      (const __attribute__((address_space(1))) void*)(gp),                    \
      (__attribute__((address_space(3))) void*)(lp), 16, 0, 0)

// raw barrier (no vmcnt(0) drain) with compiler memory fences on both sides
#define BARRIER() do { asm volatile("" ::: "memory");                         \
  __builtin_amdgcn_s_barrier(); asm volatile("" ::: "memory"); } while (0)

// ------------------------------------------------------------------ head ----
// One launch, three independent jobs (all barrier-free). Weight cvt first
// (feeds the immediately-following qkv GEMM):
//   blocks [0, 2048)    : f32->bf16 weight conversion (float4-wide).
//   blocks [2048, 4096) : preln block-1, WAVE-PER-TOKEN (4 tokens/block).
//   block 4096, thr 0   : Sinkhorn(4x4,20) + softmax(4) x2 -> HS.
#define CVT_NQ 442368      // 2304*768/4
#define CVT_NP 147456      // 768*768/4
#define CVT_N1 589824      // 3072*768/4
#define CVT_TOT (CVT_NQ + CVT_NP + 2 * CVT_N1)   // 1769472
__global__ __launch_bounds__(256) void head_kernel(
    const float* __restrict__ x, const float* __restrict__ ln1_g,
    const float* __restrict__ ln1_b, bf16* __restrict__ LN,
    const float* __restrict__ qw, const float* __restrict__ pw,
    const float* __restrict__ f1w, const float* __restrict__ f2w,
    bf16* __restrict__ Wq, bf16* __restrict__ Wp,
    bf16* __restrict__ W1, bf16* __restrict__ W2,
    const float* ar, const float* ap, const float* ao,
    const float* mr, const float* mp, const float* mo, float* HS) {
  const int tid = threadIdx.x;
  if (blockIdx.x < 2048) {
    // ---- weight cvt ----
    int i = blockIdx.x * 256 + tid;
    const int st = 2048 * 256;
    for (; i < CVT_TOT; i += st) {
      const float* src; bf16* dst; int off;
      if (i < CVT_NQ)                      { src = qw;  dst = Wq; off = i; }
      else if (i < CVT_NQ + CVT_NP)        { src = pw;  dst = Wp; off = i - CVT_NQ; }
      else if (i < CVT_NQ + CVT_NP + CVT_N1){ src = f1w; dst = W1; off = i - CVT_NQ - CVT_NP; }
      else                                 { src = f2w; dst = W2; off = i - CVT_NQ - CVT_NP - CVT_N1; }
      const float4 v = ((const float4*)src)[off];
      bf16x4 o = {(bf16)v.x, (bf16)v.y, (bf16)v.z, (bf16)v.w};
      *(bf16x4*)(dst + (size_t)off * 4) = o;
    }
    return;
  }
  if (blockIdx.x == 4096) {
    // ---- Sinkhorn + softmaxes -> HS ----
    if (tid != 0) return;
    const float* L[2] = {ar, mr};
    const float* P[2] = {ap, mp};
    const float* O[2] = {ao, mo};
    for (int s = 0; s < 2; ++s) {
      float A[16];
      for (int i = 0; i < 16; ++i) A[i] = expf(L[s][i]);
      for (int it = 0; it < 20; ++it) {
        for (int r = 0; r < 4; ++r) {
          float rs = A[4*r] + A[4*r+1] + A[4*r+2] + A[4*r+3] + 1e-8f;
          for (int c = 0; c < 4; ++c) A[4*r+c] /= rs;
        }
        for (int c = 0; c < 4; ++c) {
          float cs = A[c] + A[4+c] + A[8+c] + A[12+c] + 1e-8f;
          for (int r = 0; r < 4; ++r) A[4*r+c] /= cs;
        }
      }
      float* dst = HS + s * 24;
      for (int i = 0; i < 16; ++i) dst[i] = A[i];
      {
        float m = fmaxf(fmaxf(P[s][0], P[s][1]), fmaxf(P[s][2], P[s][3]));
        float e[4], t = 0.f;
        for (int i = 0; i < 4; ++i) { e[i] = expf(P[s][i] - m); t += e[i]; }
        for (int i = 0; i < 4; ++i) dst[16 + i] = e[i] / t;
      }
      {
        float m = fmaxf(fmaxf(O[s][0], O[s][1]), fmaxf(O[s][2], O[s][3]));
        float e[4], t = 0.f;
        for (int i = 0; i < 4; ++i) { e[i] = expf(O[s][i] - m); t += e[i]; }
        for (int i = 0; i < 4; ++i) dst[20 + i] = e[i] / t;
      }
    }
    return;
  }
  // ---- preln, wave-per-token: lane l owns c in {l, l+64, l+128} ----
  const int t = (blockIdx.x - 2048) * 4 + (tid >> 6);
  const int l = tid & 63;
  float H0, H1, H2, H3;
  {
    const float p0 = ap[0], p1 = ap[1], p2 = ap[2], p3 = ap[3];
    const float m = fmaxf(fmaxf(p0, p1), fmaxf(p2, p3));
    const float e0 = __expf(p0 - m), e1 = __expf(p1 - m),
                e2 = __expf(p2 - m), e3 = __expf(p3 - m);
    const float inv = 1.f / (e0 + e1 + e2 + e3);
    H0 = e0 * inv; H1 = e1 * inv; H2 = e2 * inv; H3 = e3 * inv;
  }
  const float* xr = x + (size_t)t * EMBED;
  float sv[3];
  #pragma unroll
  for (int k = 0; k < 3; ++k) {
    const int c = l + 64 * k;
    sv[k] = H0*xr[c] + H1*xr[CHUNK+c] + H2*xr[2*CHUNK+c] + H3*xr[3*CHUNK+c];
  }
  float sum = sv[0] + sv[1] + sv[2];
  float sq  = sv[0]*sv[0] + sv[1]*sv[1] + sv[2]*sv[2];
  #pragma unroll
  for (int m = 1; m < 64; m <<= 1) {
    sum += __shfl_xor(sum, m);
    sq  += __shfl_xor(sq, m);
  }
  const float mu = sum * (1.f / CHUNK);
  const float rs = rsqrtf(sq * (1.f / CHUNK) - mu * mu + 1e-5f);
  bf16* orow = LN + (size_t)t * EMBED;
  #pragma unroll
  for (int k = 0; k < 3; ++k) {
    const int c = l + 64 * k;
    const float sn = (sv[k] - mu) * rs;
    #pragma unroll
    for (int n = 0; n < 4; ++n) {
      const int d = n * CHUNK + c;
      orow[d] = (bf16)(sn * ln1_g[d] + ln1_b[d]);
    }
  }
}

// ----------------------------------------------------------------- gemm ----
// VERBATIM R14 core (passed timed replays): 128x128 tile, BK=32,
// 32x32x16 MFMA, 3-buffer LDS ring (STAGE t+2 -> vmcnt(8) -> barrier).
// XCD row-band block remap (index-only). KSPLIT=2: blockIdx.z halves K;
// z=1 -> C1, no bias. All outputs bf16.
template <int GELU, int KSPLIT>
__global__ __launch_bounds__(256, 2) void gemm_bt(
    const bf16* __restrict__ A, const bf16* __restrict__ B,
    const float* __restrict__ bias, bf16* __restrict__ C0,
    bf16* __restrict__ C1, int M, int N, int K) {
  constexpr int BM = 128, BN = 128, BK = 32;
  __shared__ bf16 sA[3][BM * BK];
  __shared__ bf16 sB[3][BN * BK];
  const int tid  = threadIdx.x;
  const int lane = tid & 63;
  const int Lw = blockIdx.y * gridDim.x + blockIdx.x;
  const int bandRows = gridDim.y >> 3;
  const int j = Lw >> 3;
  const int colIdx = j / bandRows;
  const int rowLoc = j - colIdx * bandRows;
  const int bm = ((Lw & 7) * bandRows + rowLoc) * BM;
  const int bn = colIdx * BN;
  const int wave = tid >> 6;
  const int wr = (wave >> 1) * 64;
  const int wc = (wave & 1) * 64;
  f32x16 acc[2][2] = {};
  const int tr = tid >> 2;
  const int gt = tid & 3;
  const int gsw = (gt ^ ((tr >> 1) & 3)) * 8;   // inverse-swizzled source granule
  const int kbeg = (KSPLIT > 1) ? blockIdx.z * (K / KSPLIT) : 0;
  const bf16* Ag = A + (size_t)(bm + tr) * K + kbeg + gsw;
  const bf16* Bg = B + (size_t)(bn + tr) * K + kbeg + gsw;
  const int lofs = tr * BK + gt * 8;
  const int r31 = lane & 31, rh = lane >> 5;
  const int asw = (r31 >> 1) & 3;               // read-side swizzle (row bits 2:1)
  const int nst = K / KSPLIT / BK;
#define STAGE(buf, t)                                                         \
  do { const int bk_ = (t) * BK;                                              \
    GLDS16(Ag + bk_, sA[buf] + lofs);                                         \
    GLDS16(Ag + (size_t)64 * K + bk_, sA[buf] + lofs + 64 * BK);              \
    GLDS16(Bg + bk_, sB[buf] + lofs);                                         \
    GLDS16(Bg + (size_t)64 * K + bk_, sB[buf] + lofs + 64 * BK);              \
  } while (0)
  STAGE(0, 0);
  STAGE(1, 1);
  int cur = 0;
  for (int t = 0; t < nst; ++t) {
    if (t + 2 < nst) {
      const int nb = cur + 2 >= 3 ? cur - 1 : cur + 2;
      STAGE(nb, t + 2);
      asm volatile("s_waitcnt vmcnt(8)" ::: "memory");
    } else if (t + 1 < nst) {
      asm volatile("s_waitcnt vmcnt(4)" ::: "memory");
    } else {
      asm volatile("s_waitcnt vmcnt(0)" ::: "memory");
    }
    BARRIER();
    bf16x8 af[2][2], bfr[2][2];
    #pragma unroll
    for (int ks = 0; ks < 2; ++ks) {
      const int pos = ((ks * 2 + rh) ^ asw) * 8;
      #pragma unroll
      for (int i = 0; i < 2; ++i) {
        af[i][ks]  = *(const bf16x8*)(sA[cur] + (wr + i * 32 + r31) * BK + pos);
        bfr[i][ks] = *(const bf16x8*)(sB[cur] + (wc + i * 32 + r31) * BK + pos);
      }
    }
    #pragma unroll
    for (int ks = 0; ks < 2; ++ks)
      #pragma unroll
      for (int i = 0; i < 2; ++i)
        #pragma unroll
        for (int j2 = 0; j2 < 2; ++j2)
          acc[i][j2] = __builtin_amdgcn_mfma_f32_32x32x16_bf16(af[i][ks], bfr[j2][ks], acc[i][j2], 0, 0, 0);
    BARRIER();
    cur = cur == 2 ? 0 : cur + 1;
  }
#undef STAGE
  // C/D 32x32 layout: col = lane&31, row = (reg&3) + 8*(reg>>2) + 4*(lane>>5)
  const bool second = (KSPLIT > 1) && (blockIdx.z != 0);
  bf16* Co = second ? C1 : C0;
  #pragma unroll
  for (int j2 = 0; j2 < 2; ++j2) {
    const int col = bn + wc + j2 * 32 + r31;
    const float bv = second ? 0.f : bias[col];
    #pragma unroll
    for (int i = 0; i < 2; ++i) {
      const int row0 = bm + wr + i * 32 + 4 * rh;
      #pragma unroll
      for (int reg = 0; reg < 16; ++reg) {
        const int row = row0 + (reg & 3) + 8 * (reg >> 2);
        float v = acc[i][j2][reg] + bv;
        if (GELU) {
          float u = 0.7978845608f * (v + 0.044715f * v * v * v);
          u = fmaxf(fminf(u, 15.f), -15.f);
          const float e = __expf(-2.f * u);
          v = v / (1.f + e);             // 0.5*v*(1+tanh(u)) == v/(1+e^{-2u})
        }
        Co[(size_t)row * N + col] = (bf16)v;
      }
    }
  }
}

// ------------------------------------------------------------------- vt ----
__global__ __launch_bounds__(256) void vt_kernel(const bf16* __restrict__ qkv,
                                                 bf16* __restrict__ VT) {
  const int tt = blockIdx.x;   // 16 tok tiles of 64
  const int bh = blockIdx.y;   // 96
  const int bb = bh / HEADS;
  const int h = bh - bb * HEADS;
  __shared__ bf16 sT[64 * 64];
  const int t = threadIdx.x;
  const int srow = t >> 3;            // 0..31 (tok within half-tile)
  const int g = t & 7;                // 16B granule
  const int gs = ((g ^ (srow & 7)) * 8);
  const bf16* Vg = qkv + ((size_t)(bb * SEQ + tt * 64 + srow)) * 2304 + 1536 + h * 64;
  GLDS16(Vg + gs, sT + srow * 64 + g * 8);
  GLDS16(Vg + (size_t)32 * 2304 + gs, sT + (32 + srow) * 64 + g * 8);
  __syncthreads();
  const int hd = t >> 2;
  const int tg = (t & 3) * 16;
  bf16 tmp[16];
  #pragma unroll
  for (int j = 0; j < 16; ++j) {
    const int tok = tg + j;
    tmp[j] = sT[tok * 64 + (hd ^ ((tok & 7) << 3))];
  }
  bf16* op = VT + (size_t)bh * (HD * SEQ) + (size_t)hd * SEQ + tt * 64 + tg;
  *(bf16x8*)(op) = *(const bf16x8*)(tmp);
  *(bf16x8*)(op + 8) = *(const bf16x8*)(tmp + 8);
}

// ----------------------------------------------------------------- attn ----
// 32x32-MFMA recast: 4 waves x 32 q-rows (QBLK=128, 256 threads). Same
// proven sync skeleton (2-buffer K/V ring, stage-at-top, counted vmcnt(4),
// 2 barriers/tile). LDS reads per 32 q-rows drop 40 -> 28 b128 (-30%).
// Fixed-max softmax (|s/8| bounded); row-sum via shared ones-tile MFMA
// (row-constant data => swizzle-invariant, written once pre-barrier).
// Fragment layouts = the GEMM-verified 32x32 mappings. sP aliases sQ.
__global__ __launch_bounds__(256) void attn_kernel(
    const bf16* __restrict__ qkv, const bf16* __restrict__ VT,
    bf16* __restrict__ out) {
  const int lin = blockIdx.x;            // 768 blocks
  const int qt = (lin >> 3) & 7;         // 8 q-tiles of 128
  const int bh = (lin & 7) + 8 * (lin >> 6);
  const int bb = bh / HEADS;
  const int h = bh - bb * HEADS;
  const int tid = threadIdx.x;
  const int lane = tid & 63;
  const int wave = tid >> 6;             // 0..3
  const size_t tokBase = (size_t)bb * SEQ;
  const int q0 = qt * 128;

  __shared__ bf16 sQ[128 * 64];     // 16 KB; aliased as sP (4 waves x 32x64)
  __shared__ bf16 sK[2][64 * 64];   // 16 KB
  __shared__ bf16 sV[2][64 * 64];   // 16 KB
  __shared__ bf16 sOnes[32 * 64];   // 4 KB; logical row0 = 1, rows 1..31 = 0

  // ones-tile: value depends only on row => physical layout == logical
  for (int idx = tid; idx < 32 * 64; idx += 256)
    sOnes[idx] = (idx < 64) ? (bf16)1.f : (bf16)0.f;

  // Q staging: 128 rows x 8 granules = 1024 slots; 4 per thread
  #pragma unroll
  for (int kq = 0; kq < 4; ++kq) {
    const int slot = tid + kq * 256;
    const int qr = slot >> 3;
    const int qg = slot & 7;
    const bf16* Qg = qkv + (tokBase + q0 + qr) * 2304 + h * 64;
    GLDS16(Qg + ((qg ^ (qr & 7)) * 8), sQ + qr * 64 + qg * 8);
  }
  // K/V staging: 64 rows x 8 granules = 512 slots each; 2+2 per thread
  const int sr0 = tid >> 3;           // 0..31
  const int g = tid & 7;
  const bf16* Kbase = qkv + tokBase * 2304 + 768 + h * 64;
  const bf16* Vbase = VT + (size_t)bh * (HD * SEQ);
#define STAGEKV(buf, kb)                                                      \
  do {                                                                        \
    _Pragma("unroll")                                                         \
    for (int hf = 0; hf < 2; ++hf) {                                          \
      const int row = sr0 + hf * 32;                                          \
      const int gsw = (g ^ (row & 7)) * 8;                                    \
      GLDS16(Kbase + (size_t)((kb) + row) * 2304 + gsw,                       \
             sK[buf] + row * 64 + g * 8);                                     \
      GLDS16(Vbase + (size_t)row * SEQ + (kb) + gsw,                          \
             sV[buf] + row * 64 + g * 8);                                     \
    }                                                                         \
  } while (0)
  STAGEKV(0, 0);
  __syncthreads();   // drains Q + tile0 loads, publishes sOnes

  const int r31 = lane & 31, rh = lane >> 5;
  // A-frag (Q): rows wave*32 + r31, k-chunks ks*16 + rh*8 (32x32x16 layout)
  bf16x8 qf[4];
  {
    const int qrow = wave * 32 + r31;
    const int qsw = (qrow & 7) << 3;
    #pragma unroll
    for (int ks = 0; ks < 4; ++ks)
      qf[ks] = *(const bf16x8*)(sQ + qrow * 64 + ((ks * 16 + rh * 8) ^ qsw));
  }
  // drain this wave's qf ds_reads before any wave can overwrite sQ (as sP)
  asm volatile("s_waitcnt lgkmcnt(0)" ::: "memory");

  f32x16 o[2] = {};
  f32x16 o2 = {};
  const int psw31 = (r31 & 7) << 3;

  for (int it = 0; it < SEQ / 64; ++it) {
    const int cur = it & 1;
    if (it + 1 < SEQ / 64) {
      STAGEKV(cur ^ 1, (it + 1) * 64);
      asm volatile("s_waitcnt vmcnt(4)" ::: "memory");
    } else {
      asm volatile("s_waitcnt vmcnt(0)" ::: "memory");
    }
    BARRIER();
    // S = Q K^T : two 32x32 tiles (j = tok half)
    f32x16 s[2] = {};
    __builtin_amdgcn_s_setprio(1);
    #pragma unroll
    for (int ks = 0; ks < 4; ++ks) {
      const int pos = ks * 16 + rh * 8;
      #pragma unroll
      for (int j = 0; j < 2; ++j) {
        const int krow = j * 32 + r31;
        bf16x8 kf = *(const bf16x8*)(sK[cur] + krow * 64 + (pos ^ ((krow & 7) << 3)));
        s[j] = __builtin_amdgcn_mfma_f32_32x32x16_bf16(qf[ks], kf, s[j], 0, 0, 0);
      }
    }
    __builtin_amdgcn_s_setprio(0);
    // fixed-max softmax numerator: p = exp(s/8); store to sP (aliased sQ)
    // D layout: col(tok) = r31 + j*32, row(q) = (r&3)+8*(r>>2)+4*rh
    bf16* Pw = sQ + wave * (32 * 64);
    #pragma unroll
    for (int j = 0; j < 2; ++j)
      #pragma unroll
      for (int r = 0; r < 16; ++r) {
        const int prow = (r & 3) + 8 * (r >> 2) + 4 * rh;
        const int col = j * 32 + r31;
        Pw[prow * 64 + (col ^ ((prow & 7) << 3))] = (bf16)__expf(s[j][r] * 0.125f);
      }
    // O += P V ; o2 accumulates row-sum via ones-tile
    __builtin_amdgcn_s_setprio(1);
    #pragma unroll
    for (int ks = 0; ks < 4; ++ks) {
      const int pos = ks * 16 + rh * 8;
      bf16x8 pa = *(const bf16x8*)(Pw + r31 * 64 + (pos ^ psw31));
      #pragma unroll
      for (int j2 = 0; j2 < 2; ++j2) {
        const int vrow = j2 * 32 + r31;
        bf16x8 vb = *(const bf16x8*)(sV[cur] + vrow * 64 + (pos ^ ((vrow & 7) << 3)));
        o[j2] = __builtin_amdgcn_mfma_f32_32x32x16_bf16(pa, vb, o[j2], 0, 0, 0);
      }
      bf16x8 ob = *(const bf16x8*)(sOnes + r31 * 64 + pos);  // row-const: linear ok
      o2 = __builtin_amdgcn_mfma_f32_32x32x16_bf16(pa, ob, o2, 0, 0, 0);
    }
    __builtin_amdgcn_s_setprio(0);
    BARRIER();
  }
#undef STAGEKV
  // epilogue: lsum = D2[q][0] (held by lanes r31==0); broadcast per hi-half
  #pragma unroll
  for (int r = 0; r < 16; ++r) {
    const int q = (r & 3) + 8 * (r >> 2) + 4 * rh;
    const float lsum = __shfl(o2[r], rh << 5, 64);
    const float inv = 1.f / lsum;
    const size_t row = tokBase + q0 + wave * 32 + q;
    bf16* orow = out + row * EMBED + h * 64;
    #pragma unroll
    for (int j2 = 0; j2 < 2; ++j2)
      orow[j2 * 32 + r31] = (bf16)(o[j2][r] * inv);
  }
}

// -------------------------------------------------------- combine+preln ----
// WAVE-PER-TOKEN (4 tokens / 256-thr block, barrier-free). X2 bf16.
template <int TWO>
__global__ __launch_bounds__(256) void combine_preln_kernel(
    const float* __restrict__ x, const bf16* __restrict__ t,
    const bf16* __restrict__ t2,
    const float* __restrict__ Hres, const float* __restrict__ Hpost,
    const float* __restrict__ Hpre2,
    const float* __restrict__ g2, const float* __restrict__ b2,
    bf16* __restrict__ X2, bf16* __restrict__ LN) {
  const int tok = blockIdx.x * 4 + (threadIdx.x >> 6);
  const int l = threadIdx.x & 63;
  const float* xr = x + (size_t)tok * EMBED;
  const bf16* tr = t + (size_t)tok * EMBED;
  const bf16* t2r = t2 + (size_t)tok * EMBED;
  bf16* orow = X2 + (size_t)tok * EMBED;
  const float Hr0 = Hres[0], Hr1 = Hres[1], Hr2 = Hres[2], Hr3 = Hres[3];
  const float Hr4 = Hres[4], Hr5 = Hres[5], Hr6 = Hres[6], Hr7 = Hres[7];
  const float Hr8 = Hres[8], Hr9 = Hres[9], HrA = Hres[10], HrB = Hres[11];
  const float HrC = Hres[12], HrD = Hres[13], HrE = Hres[14], HrF = Hres[15];
  const float Hp0 = Hpost[0], Hp1 = Hpost[1], Hp2 = Hpost[2], Hp3 = Hpost[3];
  const float He0 = Hpre2[0], He1 = Hpre2[1], He2 = Hpre2[2], He3 = Hpre2[3];
  float sv[3];
  #pragma unroll
  for (int k = 0; k < 3; ++k) {
    const int c = l + 64 * k;
    const float x0 = xr[c], x1 = xr[CHUNK + c], x2v = xr[2 * CHUNK + c], x3 = xr[3 * CHUNK + c];
    float tm = (float)tr[c] + (float)tr[CHUNK + c] + (float)tr[2 * CHUNK + c] + (float)tr[3 * CHUNK + c];
    if (TWO)
      tm += (float)t2r[c] + (float)t2r[CHUNK + c] + (float)t2r[2 * CHUNK + c] + (float)t2r[3 * CHUNK + c];
    tm *= 0.25f;
    const float v0 = Hr0*x0 + Hr1*x1 + Hr2*x2v + Hr3*x3 + Hp0 * tm;
    const float v1 = Hr4*x0 + Hr5*x1 + Hr6*x2v + Hr7*x3 + Hp1 * tm;
    const float v2 = Hr8*x0 + Hr9*x1 + HrA*x2v + HrB*x3 + Hp2 * tm;
    const float v3 = HrC*x0 + HrD*x1 + HrE*x2v + HrF*x3 + Hp3 * tm;
    orow[c] = (bf16)v0;
    orow[CHUNK + c] = (bf16)v1;
    orow[2 * CHUNK + c] = (bf16)v2;
    orow[3 * CHUNK + c] = (bf16)v3;
    sv[k] = He0 * v0 + He1 * v1 + He2 * v2 + He3 * v3;
  }
  float sum = sv[0] + sv[1] + sv[2];
  float sq  = sv[0]*sv[0] + sv[1]*sv[1] + sv[2]*sv[2];
  #pragma unroll
  for (int m = 1; m < 64; m <<= 1) {
    sum += __shfl_xor(sum, m);
    sq  += __shfl_xor(sq, m);
  }
  const float mu = sum * (1.f / CHUNK);
  const float rs = rsqrtf(sq * (1.f / CHUNK) - mu * mu + 1e-5f);
  bf16* lrow = LN + (size_t)tok * EMBED;
  #pragma unroll
  for (int k = 0; k < 3; ++k) {
    const int c = l + 64 * k;
    const float sn = (sv[k] - mu) * rs;
    #pragma unroll
    for (int n = 0; n < 4; ++n) {
      const int d = n * CHUNK + c;
      lrow[d] = (bf16)(sn * g2[d] + b2[d]);
    }
  }
}

// -------------------------------------------------------------- combine ----
// Final combine (writes f32 d_out). xs bf16. TWO=1: t + t2 (split-K).
template <int TWO>
__global__ void combine_kernel(const bf16* __restrict__ xs, const bf16* __restrict__ t,
                               const bf16* __restrict__ t2,
                               const float* __restrict__ Hres, const float* __restrict__ Hpost,
                               float* __restrict__ outp) {
  const int idx = blockIdx.x * 256 + threadIdx.x;
  if (idx >= TOKENS * CHUNK) return;
  const int tok = idx / CHUNK;
  const int c = idx - tok * CHUNK;
  const bf16* xr = xs + (size_t)tok * EMBED + c;
  const bf16* tr = t + (size_t)tok * EMBED + c;
  const float x0 = (float)xr[0], x1 = (float)xr[CHUNK],
              x2 = (float)xr[2 * CHUNK], x3 = (float)xr[3 * CHUNK];
  float tm = (float)tr[0] + (float)tr[CHUNK] + (float)tr[2 * CHUNK] + (float)tr[3 * CHUNK];
  if (TWO) {
    const bf16* t2r = t2 + (size_t)tok * EMBED + c;
    tm += (float)t2r[0] + (float)t2r[CHUNK] + (float)t2r[2 * CHUNK] + (float)t2r[3 * CHUNK];
  }
  tm *= 0.25f;
  #pragma unroll
  for (int n = 0; n < 4; ++n) {
    const float v = Hres[4*n+0]*x0 + Hres[4*n+1]*x1 + Hres[4*n+2]*x2 + Hres[4*n+3]*x3
                  + Hpost[n] * tm;
    outp[(size_t)tok * EMBED + n * CHUNK + c] = v;
  }
}

// ---------------------------------------------------------------- launch ---
extern "C" void kernel_launch(void* const* d_in, const int* in_sizes, int n_in,
                              void* d_out, int out_size, void* d_ws, size_t ws_size,
                              hipStream_t stream) {
  const float* x       = (const float*)d_in[0];
  const float* ln1_g   = (const float*)d_in[1];
  const float* ln1_b   = (const float*)d_in[2];
  const float* ln2_g   = (const float*)d_in[3];
  const float* ln2_b   = (const float*)d_in[4];
  const float* qkv_w   = (const float*)d_in[5];
  const float* qkv_b   = (const float*)d_in[6];
  const float* proj_w  = (const float*)d_in[7];
  const float* proj_b  = (const float*)d_in[8];
  const float* fc1_w   = (const float*)d_in[9];
  const float* fc1_b   = (const float*)d_in[10];
  const float* fc2_w   = (const float*)d_in[11];
  const float* fc2_b   = (const float*)d_in[12];
  const float* a_hres  = (const float*)d_in[13];
  const float* a_hpre  = (const float*)d_in[14];
  const float* a_hpost = (const float*)d_in[15];
  const float* m_hres  = (const float*)d_in[16];
  const float* m_hpre  = (const float*)d_in[17];
  const float* m_hpost = (const float*)d_in[18];

  char* ws = (char*)d_ws;
  float* HS = (float*)(ws);                                  // 48 floats
  bf16* Wq  = (bf16*)(ws + 1024);                            // 2304x768
  bf16* Wp  = (bf16*)(ws + 1024 + 3538944);                  // 768x768
  bf16* W1  = (bf16*)(ws + 1024 + 3538944 + 1179648);        // 3072x768
  bf16* W2  = (bf16*)(ws + 1024 + 3538944 + 1179648 + 4718592); // 768x3072
  bf16* LN  = (bf16*)(ws + 14156800);                        // 8192x768 bf16
  bf16* T   = (bf16*)(ws + 26739712);                        // 8192x768 bf16
  bf16* PT  = (bf16*)(ws + 39322624);                        // 8192x768 bf16 (split-K partial)
  bf16* X2  = (bf16*)(ws + 51905536);                        // 8192x768 bf16
  bf16* QKV = (bf16*)(ws + 77071360);                        // 8192x2304 bf16
  bf16* AO  = (bf16*)(ws + 114820096);                       // 8192x768 bf16
  bf16* Hm  = (bf16*)(ws + 77071360);                        // 8192x3072 (overlays QKV+AO)
  bf16* VT  = LN;   // 96x64x1024 bf16 — overlays LN (dead after qkv GEMM)

  head_kernel<<<4097, 256, 0, stream>>>(
      x, ln1_g, ln1_b, LN,
      qkv_w, proj_w, fc1_w, fc2_w, Wq, Wp, W1, W2,
      a_hres, a_hpre, a_hpost, m_hres, m_hpre, m_hpost, HS);

  // ---- block 1: attention mhc ----
  gemm_bt<0, 1><<<dim3(2304 / 128, TOKENS / 128), 256, 0, stream>>>(
      LN, Wq, qkv_b, QKV, nullptr, TOKENS, 2304, 768);
  vt_kernel<<<dim3(16, 96), 256, 0, stream>>>(QKV, VT);
  attn_kernel<<<768, 256, 0, stream>>>(QKV, VT, AO);
  gemm_bt<0, 2><<<dim3(768 / 128, TOKENS / 128, 2), 256, 0, stream>>>(
      AO, Wp, proj_b, T, PT, TOKENS, 768, 768);
  combine_preln_kernel<1><<<TOKENS / 4, 256, 0, stream>>>(
      x, T, PT, HS + 0, HS + 20, HS + 24 + 16, ln2_g, ln2_b, X2, LN);

  // ---- block 2: MLP mhc ----
  gemm_bt<1, 1><<<dim3(3072 / 128, TOKENS / 128), 256, 0, stream>>>(
      LN, W1, fc1_b, Hm, nullptr, TOKENS, 3072, 768);
  gemm_bt<0, 2><<<dim3(768 / 128, TOKENS / 128, 2), 256, 0, stream>>>(
      Hm, W2, fc2_b, T, PT, TOKENS, 768, 3072);
  combine_kernel<1><<<(TOKENS * CHUNK + 255) / 256, 256, 0, stream>>>(
      X2, T, PT, HS + 24, HS + 24 + 20, (float*)d_out);
}

// Round 20
// 305.464 us; speedup vs baseline: 1.0595x; 1.0595x over previous
//
#include <hip/hip_runtime.h>
#include <hip/hip_bf16.h>
#include <cstdint>
#include <cstddef>

#define EMBED 768
#define STREAMS 4
#define CHUNK 192          // EMBED / STREAMS
#define HEADS 12
#define HD 64
#define SEQ 1024
#define BATCH 8
#define TOKENS (BATCH * SEQ)   // 8192
#define MLPH 3072

typedef __bf16 bf16;
typedef __bf16 bf16x4 __attribute__((ext_vector_type(4)));
typedef __bf16 bf16x8 __attribute__((ext_vector_type(8)));
typedef float f32x4 __attribute__((ext_vector_type(4)));
typedef float f32x16 __attribute__((ext_vector_type(16)));

// async global->LDS, 16B per lane; LDS dest must be linear in lane order
#define GLDS16(gp, lp)                                                        \
  __builtin_amdgcn_global_load_lds(                                           \
      (const __attribute__((address_space(1))) void*)(gp),                    \
      (__attribute__((address_space(3))) void*)(lp), 16, 0, 0)

// raw barrier (no vmcnt(0) drain) with compiler memory fences on both sides
#define BARRIER() do { asm volatile("" ::: "memory");                         \
  __builtin_amdgcn_s_barrier(); asm volatile("" ::: "memory"); } while (0)

// ------------------------------------------------------------------ head ----
// One launch, three independent jobs (all barrier-free). Weight cvt first
// (feeds the immediately-following qkv GEMM):
//   blocks [0, 2048)    : f32->bf16 weight conversion (float4-wide).
//   blocks [2048, 4096) : preln block-1, WAVE-PER-TOKEN (4 tokens/block).
//   block 4096, thr 0   : Sinkhorn(4x4,20) + softmax(4) x2 -> HS.
#define CVT_NQ 442368      // 2304*768/4
#define CVT_NP 147456      // 768*768/4
#define CVT_N1 589824      // 3072*768/4
#define CVT_TOT (CVT_NQ + CVT_NP + 2 * CVT_N1)   // 1769472
__global__ __launch_bounds__(256) void head_kernel(
    const float* __restrict__ x, const float* __restrict__ ln1_g,
    const float* __restrict__ ln1_b, bf16* __restrict__ LN,
    const float* __restrict__ qw, const float* __restrict__ pw,
    const float* __restrict__ f1w, const float* __restrict__ f2w,
    bf16* __restrict__ Wq, bf16* __restrict__ Wp,
    bf16* __restrict__ W1, bf16* __restrict__ W2,
    const float* ar, const float* ap, const float* ao,
    const float* mr, const float* mp, const float* mo, float* HS) {
  const int tid = threadIdx.x;
  if (blockIdx.x < 2048) {
    // ---- weight cvt ----
    int i = blockIdx.x * 256 + tid;
    const int st = 2048 * 256;
    for (; i < CVT_TOT; i += st) {
      const float* src; bf16* dst; int off;
      if (i < CVT_NQ)                      { src = qw;  dst = Wq; off = i; }
      else if (i < CVT_NQ + CVT_NP)        { src = pw;  dst = Wp; off = i - CVT_NQ; }
      else if (i < CVT_NQ + CVT_NP + CVT_N1){ src = f1w; dst = W1; off = i - CVT_NQ - CVT_NP; }
      else                                 { src = f2w; dst = W2; off = i - CVT_NQ - CVT_NP - CVT_N1; }
      const float4 v = ((const float4*)src)[off];
      bf16x4 o = {(bf16)v.x, (bf16)v.y, (bf16)v.z, (bf16)v.w};
      *(bf16x4*)(dst + (size_t)off * 4) = o;
    }
    return;
  }
  if (blockIdx.x == 4096) {
    // ---- Sinkhorn + softmaxes -> HS ----
    if (tid != 0) return;
    const float* L[2] = {ar, mr};
    const float* P[2] = {ap, mp};
    const float* O[2] = {ao, mo};
    for (int s = 0; s < 2; ++s) {
      float A[16];
      for (int i = 0; i < 16; ++i) A[i] = expf(L[s][i]);
      for (int it = 0; it < 20; ++it) {
        for (int r = 0; r < 4; ++r) {
          float rs = A[4*r] + A[4*r+1] + A[4*r+2] + A[4*r+3] + 1e-8f;
          for (int c = 0; c < 4; ++c) A[4*r+c] /= rs;
        }
        for (int c = 0; c < 4; ++c) {
          float cs = A[c] + A[4+c] + A[8+c] + A[12+c] + 1e-8f;
          for (int r = 0; r < 4; ++r) A[4*r+c] /= cs;
        }
      }
      float* dst = HS + s * 24;
      for (int i = 0; i < 16; ++i) dst[i] = A[i];
      {
        float m = fmaxf(fmaxf(P[s][0], P[s][1]), fmaxf(P[s][2], P[s][3]));
        float e[4], t = 0.f;
        for (int i = 0; i < 4; ++i) { e[i] = expf(P[s][i] - m); t += e[i]; }
        for (int i = 0; i < 4; ++i) dst[16 + i] = e[i] / t;
      }
      {
        float m = fmaxf(fmaxf(O[s][0], O[s][1]), fmaxf(O[s][2], O[s][3]));
        float e[4], t = 0.f;
        for (int i = 0; i < 4; ++i) { e[i] = expf(O[s][i] - m); t += e[i]; }
        for (int i = 0; i < 4; ++i) dst[20 + i] = e[i] / t;
      }
    }
    return;
  }
  // ---- preln, wave-per-token: lane l owns c in {l, l+64, l+128} ----
  const int t = (blockIdx.x - 2048) * 4 + (tid >> 6);
  const int l = tid & 63;
  float H0, H1, H2, H3;
  {
    const float p0 = ap[0], p1 = ap[1], p2 = ap[2], p3 = ap[3];
    const float m = fmaxf(fmaxf(p0, p1), fmaxf(p2, p3));
    const float e0 = __expf(p0 - m), e1 = __expf(p1 - m),
                e2 = __expf(p2 - m), e3 = __expf(p3 - m);
    const float inv = 1.f / (e0 + e1 + e2 + e3);
    H0 = e0 * inv; H1 = e1 * inv; H2 = e2 * inv; H3 = e3 * inv;
  }
  const float* xr = x + (size_t)t * EMBED;
  float sv[3];
  #pragma unroll
  for (int k = 0; k < 3; ++k) {
    const int c = l + 64 * k;
    sv[k] = H0*xr[c] + H1*xr[CHUNK+c] + H2*xr[2*CHUNK+c] + H3*xr[3*CHUNK+c];
  }
  float sum = sv[0] + sv[1] + sv[2];
  float sq  = sv[0]*sv[0] + sv[1]*sv[1] + sv[2]*sv[2];
  #pragma unroll
  for (int m = 1; m < 64; m <<= 1) {
    sum += __shfl_xor(sum, m);
    sq  += __shfl_xor(sq, m);
  }
  const float mu = sum * (1.f / CHUNK);
  const float rs = rsqrtf(sq * (1.f / CHUNK) - mu * mu + 1e-5f);
  bf16* orow = LN + (size_t)t * EMBED;
  #pragma unroll
  for (int k = 0; k < 3; ++k) {
    const int c = l + 64 * k;
    const float sn = (sv[k] - mu) * rs;
    #pragma unroll
    for (int n = 0; n < 4; ++n) {
      const int d = n * CHUNK + c;
      orow[d] = (bf16)(sn * ln1_g[d] + ln1_b[d]);
    }
  }
}

// ----------------------------------------------------------------- gemm ----
// VERBATIM R14 core (passed timed replays): 128x128 tile, BK=32,
// 32x32x16 MFMA, 3-buffer LDS ring (STAGE t+2 -> vmcnt(8) -> barrier).
// XCD row-band block remap (index-only). KSPLIT=2: blockIdx.z halves K;
// z=1 -> C1, no bias. All outputs bf16.
template <int GELU, int KSPLIT>
__global__ __launch_bounds__(256, 2) void gemm_bt(
    const bf16* __restrict__ A, const bf16* __restrict__ B,
    const float* __restrict__ bias, bf16* __restrict__ C0,
    bf16* __restrict__ C1, int M, int N, int K) {
  constexpr int BM = 128, BN = 128, BK = 32;
  __shared__ bf16 sA[3][BM * BK];
  __shared__ bf16 sB[3][BN * BK];
  const int tid  = threadIdx.x;
  const int lane = tid & 63;
  const int Lw = blockIdx.y * gridDim.x + blockIdx.x;
  const int bandRows = gridDim.y >> 3;
  const int j = Lw >> 3;
  const int colIdx = j / bandRows;
  const int rowLoc = j - colIdx * bandRows;
  const int bm = ((Lw & 7) * bandRows + rowLoc) * BM;
  const int bn = colIdx * BN;
  const int wave = tid >> 6;
  const int wr = (wave >> 1) * 64;
  const int wc = (wave & 1) * 64;
  f32x16 acc[2][2] = {};
  const int tr = tid >> 2;
  const int gt = tid & 3;
  const int gsw = (gt ^ ((tr >> 1) & 3)) * 8;   // inverse-swizzled source granule
  const int kbeg = (KSPLIT > 1) ? blockIdx.z * (K / KSPLIT) : 0;
  const bf16* Ag = A + (size_t)(bm + tr) * K + kbeg + gsw;
  const bf16* Bg = B + (size_t)(bn + tr) * K + kbeg + gsw;
  const int lofs = tr * BK + gt * 8;
  const int r31 = lane & 31, rh = lane >> 5;
  const int asw = (r31 >> 1) & 3;               // read-side swizzle (row bits 2:1)
  const int nst = K / KSPLIT / BK;
#define STAGE(buf, t)                                                         \
  do { const int bk_ = (t) * BK;                                              \
    GLDS16(Ag + bk_, sA[buf] + lofs);                                         \
    GLDS16(Ag + (size_t)64 * K + bk_, sA[buf] + lofs + 64 * BK);              \
    GLDS16(Bg + bk_, sB[buf] + lofs);                                         \
    GLDS16(Bg + (size_t)64 * K + bk_, sB[buf] + lofs + 64 * BK);              \
  } while (0)
  STAGE(0, 0);
  STAGE(1, 1);
  int cur = 0;
  for (int t = 0; t < nst; ++t) {
    if (t + 2 < nst) {
      const int nb = cur + 2 >= 3 ? cur - 1 : cur + 2;
      STAGE(nb, t + 2);
      asm volatile("s_waitcnt vmcnt(8)" ::: "memory");
    } else if (t + 1 < nst) {
      asm volatile("s_waitcnt vmcnt(4)" ::: "memory");
    } else {
      asm volatile("s_waitcnt vmcnt(0)" ::: "memory");
    }
    BARRIER();
    bf16x8 af[2][2], bfr[2][2];
    #pragma unroll
    for (int ks = 0; ks < 2; ++ks) {
      const int pos = ((ks * 2 + rh) ^ asw) * 8;
      #pragma unroll
      for (int i = 0; i < 2; ++i) {
        af[i][ks]  = *(const bf16x8*)(sA[cur] + (wr + i * 32 + r31) * BK + pos);
        bfr[i][ks] = *(const bf16x8*)(sB[cur] + (wc + i * 32 + r31) * BK + pos);
      }
    }
    #pragma unroll
    for (int ks = 0; ks < 2; ++ks)
      #pragma unroll
      for (int i = 0; i < 2; ++i)
        #pragma unroll
        for (int j2 = 0; j2 < 2; ++j2)
          acc[i][j2] = __builtin_amdgcn_mfma_f32_32x32x16_bf16(af[i][ks], bfr[j2][ks], acc[i][j2], 0, 0, 0);
    BARRIER();
    cur = cur == 2 ? 0 : cur + 1;
  }
#undef STAGE
  // C/D 32x32 layout: col = lane&31, row = (reg&3) + 8*(reg>>2) + 4*(lane>>5)
  const bool second = (KSPLIT > 1) && (blockIdx.z != 0);
  bf16* Co = second ? C1 : C0;
  #pragma unroll
  for (int j2 = 0; j2 < 2; ++j2) {
    const int col = bn + wc + j2 * 32 + r31;
    const float bv = second ? 0.f : bias[col];
    #pragma unroll
    for (int i = 0; i < 2; ++i) {
      const int row0 = bm + wr + i * 32 + 4 * rh;
      #pragma unroll
      for (int reg = 0; reg < 16; ++reg) {
        const int row = row0 + (reg & 3) + 8 * (reg >> 2);
        float v = acc[i][j2][reg] + bv;
        if (GELU) {
          float u = 0.7978845608f * (v + 0.044715f * v * v * v);
          u = fmaxf(fminf(u, 15.f), -15.f);
          const float e = __expf(-2.f * u);
          v = v / (1.f + e);             // 0.5*v*(1+tanh(u)) == v/(1+e^{-2u})
        }
        Co[(size_t)row * N + col] = (bf16)v;
      }
    }
  }
}

// ------------------------------------------------------------------- vt ----
__global__ __launch_bounds__(256) void vt_kernel(const bf16* __restrict__ qkv,
                                                 bf16* __restrict__ VT) {
  const int tt = blockIdx.x;   // 16 tok tiles of 64
  const int bh = blockIdx.y;   // 96
  const int bb = bh / HEADS;
  const int h = bh - bb * HEADS;
  __shared__ bf16 sT[64 * 64];
  const int t = threadIdx.x;
  const int srow = t >> 3;            // 0..31 (tok within half-tile)
  const int g = t & 7;                // 16B granule
  const int gs = ((g ^ (srow & 7)) * 8);
  const bf16* Vg = qkv + ((size_t)(bb * SEQ + tt * 64 + srow)) * 2304 + 1536 + h * 64;
  GLDS16(Vg + gs, sT + srow * 64 + g * 8);
  GLDS16(Vg + (size_t)32 * 2304 + gs, sT + (32 + srow) * 64 + g * 8);
  __syncthreads();
  const int hd = t >> 2;
  const int tg = (t & 3) * 16;
  bf16 tmp[16];
  #pragma unroll
  for (int j = 0; j < 16; ++j) {
    const int tok = tg + j;
    tmp[j] = sT[tok * 64 + (hd ^ ((tok & 7) << 3))];
  }
  bf16* op = VT + (size_t)bh * (HD * SEQ) + (size_t)hd * SEQ + tt * 64 + tg;
  *(bf16x8*)(op) = *(const bf16x8*)(tmp);
  *(bf16x8*)(op + 8) = *(const bf16x8*)(tmp + 8);
}

// ----------------------------------------------------------------- attn ----
// VERBATIM R18 (best measured; passed timed replays). QBLK=128, 8 waves /
// 512 threads, fixed-max softmax, ones-row MFMA row-sum, 2-buffer K/V ring,
// swizzled LDS, XCD-chunked mapping, setprio, sP aliased onto sQ
// (Q register-resident after prologue; lgkmcnt(0) drain before overwrite).
__global__ __launch_bounds__(512) void attn_kernel(
    const bf16* __restrict__ qkv, const bf16* __restrict__ VT,
    bf16* __restrict__ out) {
  const int lin = blockIdx.x;            // 768 blocks
  const int qt = (lin >> 3) & 7;         // 8 q-tiles of 128
  const int bh = (lin & 7) + 8 * (lin >> 6);
  const int bb = bh / HEADS;
  const int h = bh - bb * HEADS;
  const int tid = threadIdx.x;
  const int lane = tid & 63;
  const int wave = tid >> 6;             // 0..7
  const size_t tokBase = (size_t)bb * SEQ;
  const int q0 = qt * 128;

  __shared__ bf16 sQ[128 * 64];     // 16 KB; reused as sP after prologue
  __shared__ bf16 sK[2][64 * 64];   // 16 KB
  __shared__ bf16 sV[2][80 * 64];   // 20 KB; rows 64.. = ones row + zeros

  for (int idx = tid; idx < 16 * 64; idx += 512) {
    const bf16 v = (idx < 64) ? (bf16)1.f : (bf16)0.f;
    sV[0][64 * 64 + idx] = v;
    sV[1][64 * 64 + idx] = v;
  }

  {
    #pragma unroll
    for (int kq = 0; kq < 2; ++kq) {
      const int slot = tid + kq * 512;
      const int qr = slot >> 3;
      const int qg = slot & 7;
      const bf16* Qg = qkv + (tokBase + q0 + qr) * 2304 + h * 64;
      GLDS16(Qg + ((qg ^ (qr & 7)) * 8), sQ + qr * 64 + qg * 8);
    }
  }
  const int srow = tid >> 3;          // 0..63
  const int g = tid & 7;
  const int gs = ((g ^ (srow & 7)) * 8);
  const bf16* Kbase = qkv + tokBase * 2304 + 768 + h * 64;
  const bf16* Vbase = VT + (size_t)bh * (HD * SEQ);
  GLDS16(Kbase + (size_t)srow * 2304 + gs, sK[0] + srow * 64 + g * 8);
  GLDS16(Vbase + (size_t)srow * SEQ + gs, sV[0] + srow * 64 + g * 8);
  __syncthreads();

  const int l15 = lane & 15, hi = lane >> 4;
  const int ksw = (l15 & 7) << 3;
  bf16x8 qf[2];
  {
    const int qrow = wave * 16 + l15;
    const int qsw = (qrow & 7) << 3;
    #pragma unroll
    for (int ks = 0; ks < 2; ++ks)
      qf[ks] = *(const bf16x8*)(sQ + qrow * 64 + ((hi * 8 + ks * 32) ^ qsw));
  }
  // drain this wave's qf ds_reads before any wave can overwrite sQ (as sP)
  asm volatile("s_waitcnt lgkmcnt(0)" ::: "memory");

  f32x4 o[5] = {};

  for (int it = 0; it < SEQ / 64; ++it) {
    const int cur = it & 1;
    if (it + 1 < SEQ / 64) {
      const int kb = (it + 1) * 64;
      GLDS16(Kbase + (size_t)(kb + srow) * 2304 + gs, sK[cur ^ 1] + srow * 64 + g * 8);
      GLDS16(Vbase + (size_t)srow * SEQ + kb + gs, sV[cur ^ 1] + srow * 64 + g * 8);
      asm volatile("s_waitcnt vmcnt(2)" ::: "memory");
    } else {
      asm volatile("s_waitcnt vmcnt(0)" ::: "memory");
    }
    BARRIER();
    f32x4 s[4];
    __builtin_amdgcn_s_setprio(1);
    #pragma unroll
    for (int nj = 0; nj < 4; ++nj) {
      s[nj] = (f32x4){0.f, 0.f, 0.f, 0.f};
      #pragma unroll
      for (int ks = 0; ks < 2; ++ks) {
        bf16x8 kf = *(const bf16x8*)(sK[cur] + (nj * 16 + l15) * 64 + ((hi * 8 + ks * 32) ^ ksw));
        s[nj] = __builtin_amdgcn_mfma_f32_16x16x32_bf16(qf[ks], kf, s[nj], 0, 0, 0);
      }
    }
    __builtin_amdgcn_s_setprio(0);
    bf16* Pw = sQ + wave * (16 * 64);   // per-wave P tile (aliased onto sQ)
    #pragma unroll
    for (int r = 0; r < 4; ++r) {
      const int prow = hi * 4 + r;
      const int psw = (prow & 7) << 3;
      #pragma unroll
      for (int nj = 0; nj < 4; ++nj)
        Pw[prow * 64 + ((nj * 16 + l15) ^ psw)] = (bf16)__expf(s[nj][r] * 0.125f);
    }
    __builtin_amdgcn_s_setprio(1);
    #pragma unroll
    for (int ks = 0; ks < 2; ++ks) {
      bf16x8 pa = *(const bf16x8*)(Pw + l15 * 64 + ((hi * 8 + ks * 32) ^ ksw));
      #pragma unroll
      for (int nj = 0; nj < 5; ++nj) {
        bf16x8 vb = *(const bf16x8*)(sV[cur] + (nj * 16 + l15) * 64 + ((hi * 8 + ks * 32) ^ ksw));
        o[nj] = __builtin_amdgcn_mfma_f32_16x16x32_bf16(pa, vb, o[nj], 0, 0, 0);
      }
    }
    __builtin_amdgcn_s_setprio(0);
    BARRIER();
  }
  #pragma unroll
  for (int r = 0; r < 4; ++r) {
    const float lsum = __shfl(o[4][r], hi << 4, 64);   // lane (hi,l15=0) holds l
    const float inv = 1.f / lsum;
    const size_t row = tokBase + q0 + wave * 16 + hi * 4 + r;
    bf16* orow = out + row * EMBED + h * 64;
    #pragma unroll
    for (int nj = 0; nj < 4; ++nj)
      orow[nj * 16 + l15] = (bf16)(o[nj][r] * inv);
  }
}

// -------------------------------------------------------- combine+preln ----
// WAVE-PER-TOKEN (4 tokens / 256-thr block, barrier-free). X2 bf16.
template <int TWO>
__global__ __launch_bounds__(256) void combine_preln_kernel(
    const float* __restrict__ x, const bf16* __restrict__ t,
    const bf16* __restrict__ t2,
    const float* __restrict__ Hres, const float* __restrict__ Hpost,
    const float* __restrict__ Hpre2,
    const float* __restrict__ g2, const float* __restrict__ b2,
    bf16* __restrict__ X2, bf16* __restrict__ LN) {
  const int tok = blockIdx.x * 4 + (threadIdx.x >> 6);
  const int l = threadIdx.x & 63;
  const float* xr = x + (size_t)tok * EMBED;
  const bf16* tr = t + (size_t)tok * EMBED;
  const bf16* t2r = t2 + (size_t)tok * EMBED;
  bf16* orow = X2 + (size_t)tok * EMBED;
  const float Hr0 = Hres[0], Hr1 = Hres[1], Hr2 = Hres[2], Hr3 = Hres[3];
  const float Hr4 = Hres[4], Hr5 = Hres[5], Hr6 = Hres[6], Hr7 = Hres[7];
  const float Hr8 = Hres[8], Hr9 = Hres[9], HrA = Hres[10], HrB = Hres[11];
  const float HrC = Hres[12], HrD = Hres[13], HrE = Hres[14], HrF = Hres[15];
  const float Hp0 = Hpost[0], Hp1 = Hpost[1], Hp2 = Hpost[2], Hp3 = Hpost[3];
  const float He0 = Hpre2[0], He1 = Hpre2[1], He2 = Hpre2[2], He3 = Hpre2[3];
  float sv[3];
  #pragma unroll
  for (int k = 0; k < 3; ++k) {
    const int c = l + 64 * k;
    const float x0 = xr[c], x1 = xr[CHUNK + c], x2v = xr[2 * CHUNK + c], x3 = xr[3 * CHUNK + c];
    float tm = (float)tr[c] + (float)tr[CHUNK + c] + (float)tr[2 * CHUNK + c] + (float)tr[3 * CHUNK + c];
    if (TWO)
      tm += (float)t2r[c] + (float)t2r[CHUNK + c] + (float)t2r[2 * CHUNK + c] + (float)t2r[3 * CHUNK + c];
    tm *= 0.25f;
    const float v0 = Hr0*x0 + Hr1*x1 + Hr2*x2v + Hr3*x3 + Hp0 * tm;
    const float v1 = Hr4*x0 + Hr5*x1 + Hr6*x2v + Hr7*x3 + Hp1 * tm;
    const float v2 = Hr8*x0 + Hr9*x1 + HrA*x2v + HrB*x3 + Hp2 * tm;
    const float v3 = HrC*x0 + HrD*x1 + HrE*x2v + HrF*x3 + Hp3 * tm;
    orow[c] = (bf16)v0;
    orow[CHUNK + c] = (bf16)v1;
    orow[2 * CHUNK + c] = (bf16)v2;
    orow[3 * CHUNK + c] = (bf16)v3;
    sv[k] = He0 * v0 + He1 * v1 + He2 * v2 + He3 * v3;
  }
  float sum = sv[0] + sv[1] + sv[2];
  float sq  = sv[0]*sv[0] + sv[1]*sv[1] + sv[2]*sv[2];
  #pragma unroll
  for (int m = 1; m < 64; m <<= 1) {
    sum += __shfl_xor(sum, m);
    sq  += __shfl_xor(sq, m);
  }
  const float mu = sum * (1.f / CHUNK);
  const float rs = rsqrtf(sq * (1.f / CHUNK) - mu * mu + 1e-5f);
  bf16* lrow = LN + (size_t)tok * EMBED;
  #pragma unroll
  for (int k = 0; k < 3; ++k) {
    const int c = l + 64 * k;
    const float sn = (sv[k] - mu) * rs;
    #pragma unroll
    for (int n = 0; n < 4; ++n) {
      const int d = n * CHUNK + c;
      lrow[d] = (bf16)(sn * g2[d] + b2[d]);
    }
  }
}

// -------------------------------------------------------------- combine ----
// Final combine (writes f32 d_out). xs bf16. TWO=1: t + t2 (split-K).
template <int TWO>
__global__ void combine_kernel(const bf16* __restrict__ xs, const bf16* __restrict__ t,
                               const bf16* __restrict__ t2,
                               const float* __restrict__ Hres, const float* __restrict__ Hpost,
                               float* __restrict__ outp) {
  const int idx = blockIdx.x * 256 + threadIdx.x;
  if (idx >= TOKENS * CHUNK) return;
  const int tok = idx / CHUNK;
  const int c = idx - tok * CHUNK;
  const bf16* xr = xs + (size_t)tok * EMBED + c;
  const bf16* tr = t + (size_t)tok * EMBED + c;
  const float x0 = (float)xr[0], x1 = (float)xr[CHUNK],
              x2 = (float)xr[2 * CHUNK], x3 = (float)xr[3 * CHUNK];
  float tm = (float)tr[0] + (float)tr[CHUNK] + (float)tr[2 * CHUNK] + (float)tr[3 * CHUNK];
  if (TWO) {
    const bf16* t2r = t2 + (size_t)tok * EMBED + c;
    tm += (float)t2r[0] + (float)t2r[CHUNK] + (float)t2r[2 * CHUNK] + (float)t2r[3 * CHUNK];
  }
  tm *= 0.25f;
  #pragma unroll
  for (int n = 0; n < 4; ++n) {
    const float v = Hres[4*n+0]*x0 + Hres[4*n+1]*x1 + Hres[4*n+2]*x2 + Hres[4*n+3]*x3
                  + Hpost[n] * tm;
    outp[(size_t)tok * EMBED + n * CHUNK + c] = v;
  }
}

// ---------------------------------------------------------------- launch ---
extern "C" void kernel_launch(void* const* d_in, const int* in_sizes, int n_in,
                              void* d_out, int out_size, void* d_ws, size_t ws_size,
                              hipStream_t stream) {
  const float* x       = (const float*)d_in[0];
  const float* ln1_g   = (const float*)d_in[1];
  const float* ln1_b   = (const float*)d_in[2];
  const float* ln2_g   = (const float*)d_in[3];
  const float* ln2_b   = (const float*)d_in[4];
  const float* qkv_w   = (const float*)d_in[5];
  const float* qkv_b   = (const float*)d_in[6];
  const float* proj_w  = (const float*)d_in[7];
  const float* proj_b  = (const float*)d_in[8];
  const float* fc1_w   = (const float*)d_in[9];
  const float* fc1_b   = (const float*)d_in[10];
  const float* fc2_w   = (const float*)d_in[11];
  const float* fc2_b   = (const float*)d_in[12];
  const float* a_hres  = (const float*)d_in[13];
  const float* a_hpre  = (const float*)d_in[14];
  const float* a_hpost = (const float*)d_in[15];
  const float* m_hres  = (const float*)d_in[16];
  const float* m_hpre  = (const float*)d_in[17];
  const float* m_hpost = (const float*)d_in[18];

  char* ws = (char*)d_ws;
  float* HS = (float*)(ws);                                  // 48 floats
  bf16* Wq  = (bf16*)(ws + 1024);                            // 2304x768
  bf16* Wp  = (bf16*)(ws + 1024 + 3538944);                  // 768x768
  bf16* W1  = (bf16*)(ws + 1024 + 3538944 + 1179648);        // 3072x768
  bf16* W2  = (bf16*)(ws + 1024 + 3538944 + 1179648 + 4718592); // 768x3072
  bf16* LN  = (bf16*)(ws + 14156800);                        // 8192x768 bf16
  bf16* T   = (bf16*)(ws + 26739712);                        // 8192x768 bf16
  bf16* PT  = (bf16*)(ws + 39322624);                        // 8192x768 bf16 (split-K partial)
  bf16* X2  = (bf16*)(ws + 51905536);                        // 8192x768 bf16
  bf16* QKV = (bf16*)(ws + 77071360);                        // 8192x2304 bf16
  bf16* AO  = (bf16*)(ws + 114820096);                       // 8192x768 bf16
  bf16* Hm  = (bf16*)(ws + 77071360);                        // 8192x3072 (overlays QKV+AO)
  bf16* VT  = LN;   // 96x64x1024 bf16 — overlays LN (dead after qkv GEMM)

  head_kernel<<<4097, 256, 0, stream>>>(
      x, ln1_g, ln1_b, LN,
      qkv_w, proj_w, fc1_w, fc2_w, Wq, Wp, W1, W2,
      a_hres, a_hpre, a_hpost, m_hres, m_hpre, m_hpost, HS);

  // ---- block 1: attention mhc ----
  gemm_bt<0, 1><<<dim3(2304 / 128, TOKENS / 128), 256, 0, stream>>>(
      LN, Wq, qkv_b, QKV, nullptr, TOKENS, 2304, 768);
  vt_kernel<<<dim3(16, 96), 256, 0, stream>>>(QKV, VT);
  attn_kernel<<<768, 512, 0, stream>>>(QKV, VT, AO);
  gemm_bt<0, 2><<<dim3(768 / 128, TOKENS / 128, 2), 256, 0, stream>>>(
      AO, Wp, proj_b, T, PT, TOKENS, 768, 768);
  combine_preln_kernel<1><<<TOKENS / 4, 256, 0, stream>>>(
      x, T, PT, HS + 0, HS + 20, HS + 24 + 16, ln2_g, ln2_b, X2, LN);

  // ---- block 2: MLP mhc ----
  gemm_bt<1, 1><<<dim3(3072 / 128, TOKENS / 128), 256, 0, stream>>>(
      LN, W1, fc1_b, Hm, nullptr, TOKENS, 3072, 768);
  gemm_bt<0, 2><<<dim3(768 / 128, TOKENS / 128, 2), 256, 0, stream>>>(
      Hm, W2, fc2_b, T, PT, TOKENS, 768, 3072);
  combine_kernel<1><<<(TOKENS * CHUNK + 255) / 256, 256, 0, stream>>>(
      X2, T, PT, HS + 24, HS + 24 + 20, (float*)d_out);
}